// Round 3
// baseline (593.773 us; speedup 1.0000x reference)
//
#include <hip/hip_runtime.h>
#include <math.h>

#define N_NODES 100000
#define N_EDGES 1600000
#define F_IN 100
#define F_H 32

#define BKT_SHIFT 7
#define BKT_C 128                       // nodes per bucket
#define NBK 782                         // ceil(N_NODES / BKT_C)
#define BF_B 1024
#define BF_EPT 8
#define BF_TILE 8192                    // BF_B * BF_EPT
#define BF_GRID 196                     // ceil(N_EDGES / BF_TILE)
#define AG_B 256

// ---------------------------------------------- bucket histogram (LDS-binned)
__global__ void bhist_kernel(const int* __restrict__ dst, int* __restrict__ bcnt) {
    __shared__ int h[NBK];
    int t = threadIdx.x;
    for (int i = t; i < NBK; i += blockDim.x) h[i] = 0;
    __syncthreads();
    int stride = gridDim.x * blockDim.x;
    for (int e = blockIdx.x * blockDim.x + t; e < N_EDGES; e += stride)
        atomicAdd(&h[dst[e] >> BKT_SHIFT], 1);
    __syncthreads();
    for (int i = t; i < NBK; i += blockDim.x)
        if (h[i]) atomicAdd(&bcnt[i], h[i]);
}

// ---------------------------------------------- scan 782 bucket counts (1 block)
__global__ void bscan_kernel(const int* __restrict__ bcnt, int* __restrict__ bbase,
                             int* __restrict__ gcursor) {
    __shared__ int s[1024];
    int t = threadIdx.x;
    int v = (t < NBK) ? bcnt[t] : 0;
    s[t] = v;
    __syncthreads();
    for (int off = 1; off < 1024; off <<= 1) {
        int x = (t >= off) ? s[t - off] : 0;
        __syncthreads();
        s[t] += x;
        __syncthreads();
    }
    if (t < NBK) { int b = s[t] - v; bbase[t] = b; gcursor[t] = b; }
    if (t == 0) bbase[NBK] = N_EDGES;
}

// ---------------------------------------------- block-level counting sort into buckets
// also fuses the per-node degree histogram (counts)
__global__ __launch_bounds__(BF_B) void binfill_kernel(
        const int* __restrict__ src, const int* __restrict__ dst,
        int* __restrict__ gcursor, int* __restrict__ counts,
        unsigned* __restrict__ packed) {
    __shared__ int cnt[NBK];
    __shared__ int lbase[NBK];
    __shared__ int gbase[NBK];
    __shared__ int scanbuf[BF_B];
    __shared__ unsigned stage[BF_TILE];          // 32 KB
    __shared__ unsigned short stageB[BF_TILE];   // 16 KB
    __shared__ int tot;
    int t = threadIdx.x;
    long base = (long)blockIdx.x * BF_TILE;
    for (int i = t; i < NBK; i += BF_B) cnt[i] = 0;
    __syncthreads();
    int myb[BF_EPT]; int mypos[BF_EPT]; unsigned mypk[BF_EPT];
    for (int k = 0; k < BF_EPT; k++) {
        long e = base + t + (long)k * BF_B;      // coalesced
        myb[k] = -1;
        if (e < N_EDGES) {
            int d = dst[e];
            int sI = src[e];
            atomicAdd(&counts[d], 1);            // fused node-degree histogram
            int b = d >> BKT_SHIFT;
            myb[k] = b;
            mypk[k] = (unsigned)sI | ((unsigned)(d & (BKT_C - 1)) << 17);
            mypos[k] = atomicAdd(&cnt[b], 1);
        }
    }
    __syncthreads();
    int v = (t < NBK) ? cnt[t] : 0;
    scanbuf[t] = v;
    __syncthreads();
    for (int off = 1; off < BF_B; off <<= 1) {
        int x = (t >= off) ? scanbuf[t - off] : 0;
        __syncthreads();
        scanbuf[t] += x;
        __syncthreads();
    }
    if (t < NBK) lbase[t] = scanbuf[t] - v;
    if (t == BF_B - 1) tot = scanbuf[t];
    __syncthreads();
    if (t < NBK && v > 0) gbase[t] = atomicAdd(&gcursor[t], v);
    for (int k = 0; k < BF_EPT; k++) {
        if (myb[k] >= 0) {
            int p = lbase[myb[k]] + mypos[k];
            stage[p] = mypk[k];
            stageB[p] = (unsigned short)myb[k];
        }
    }
    __syncthreads();
    int T = tot;
    for (int i = t; i < T; i += BF_B) {          // bucket runs -> contiguous writes
        int b = stageB[i];
        packed[gbase[b] + (i - lbase[b])] = stage[i];
    }
}

// ---------------------------------------------- dinv = rsqrt(deg + 1)
__global__ void dinv_kernel(const int* __restrict__ counts, float* __restrict__ dinv) {
    int i = blockIdx.x * blockDim.x + threadIdx.x;
    if (i < N_NODES) dinv[i] = rsqrtf((float)counts[i] + 1.0f);
}

// ---------------------------------------------- h2 = (x @ Wc) * dinv[row]
// block = 256 threads = 8 rows x 32 cols
__global__ void xw_kernel(const float* __restrict__ x, const float* __restrict__ W,
                          const float* __restrict__ dinv, float* __restrict__ h2) {
    __shared__ float Ws[F_IN * F_H];
    for (int i = threadIdx.x; i < F_IN * F_H; i += blockDim.x) Ws[i] = W[i];
    __syncthreads();
    int row = blockIdx.x * 8 + (threadIdx.x >> 5);
    int col = threadIdx.x & 31;
    if (row >= N_NODES) return;
    const float4* xr4 = (const float4*)(x + (long)row * F_IN);
    float s = 0.f;
#pragma unroll
    for (int k = 0; k < 25; k++) {
        float4 v = xr4[k];
        int k4 = k * 4;
        s += v.x * Ws[k4 * F_H + col];
        s += v.y * Ws[(k4 + 1) * F_H + col];
        s += v.z * Ws[(k4 + 2) * F_H + col];
        s += v.w * Ws[(k4 + 3) * F_H + col];
    }
    h2[row * F_H + col] = s * dinv[row];
}

// ---------------------------------------------- per-bucket aggregation + fused MLP
__global__ __launch_bounds__(AG_B) void agg_kernel(
        const int* __restrict__ bbase, const unsigned* __restrict__ packed,
        const float* __restrict__ h2, const float* __restrict__ dinv,
        const float* __restrict__ bc,
        const float* __restrict__ W1, const float* __restrict__ b1,
        const float* __restrict__ W2, const float* __restrict__ b2,
        const float* __restrict__ W3, const float* __restrict__ b3,
        float* __restrict__ out) {
    __shared__ float accL[BKT_C * 33];           // stride 33: conflict-free
    __shared__ float sbc[32], sW1[512], sb1[16], sW2[128], sb2[8], sW3[80], sb3[10];
    int t = threadIdx.x;
    for (int i = t; i < BKT_C * 33; i += AG_B) accL[i] = 0.f;
    if (t < 32) sbc[t] = bc[t];
    for (int i = t; i < 512; i += AG_B) sW1[i] = W1[i];
    if (t < 16) sb1[t] = b1[t];
    if (t < 128) sW2[t] = W2[t];
    if (t < 8) sb2[t] = b2[t];
    if (t < 80) sW3[t] = W3[t];
    if (t < 10) sb3[t] = b3[t];
    __syncthreads();
    int b = blockIdx.x;
    int beg = bbase[b], end = bbase[b + 1];
    int g = t >> 5, col = t & 31;                // 8 edges per iteration
    int i = beg + g;
    for (; i + 24 < end; i += 32) {              // 4x unrolled: 4 gathers in flight
        unsigned p0 = packed[i], p1 = packed[i + 8], p2 = packed[i + 16], p3 = packed[i + 24];
        float v0 = h2[(p0 & 0x1FFFF) * F_H + col];
        float v1 = h2[(p1 & 0x1FFFF) * F_H + col];
        float v2 = h2[(p2 & 0x1FFFF) * F_H + col];
        float v3 = h2[(p3 & 0x1FFFF) * F_H + col];
        atomicAdd(&accL[(p0 >> 17) * 33 + col], v0);
        atomicAdd(&accL[(p1 >> 17) * 33 + col], v1);
        atomicAdd(&accL[(p2 >> 17) * 33 + col], v2);
        atomicAdd(&accL[(p3 >> 17) * 33 + col], v3);
    }
    for (; i < end; i += 8) {
        unsigned p = packed[i];
        float v = h2[(p & 0x1FFFF) * F_H + col];
        atomicAdd(&accL[(p >> 17) * 33 + col], v);
    }
    __syncthreads();
    int n = (b << BKT_SHIFT) + t;
    if (t < BKT_C && n < N_NODES) {
        float dv = dinv[n];
        float a[32];
        const float4* hp = (const float4*)(h2 + (long)n * F_H);
#pragma unroll
        for (int q = 0; q < 8; q++) {
            float4 hv = hp[q];
            a[q * 4 + 0] = fmaxf((accL[t * 33 + q * 4 + 0] + hv.x) * dv + sbc[q * 4 + 0], 0.f);
            a[q * 4 + 1] = fmaxf((accL[t * 33 + q * 4 + 1] + hv.y) * dv + sbc[q * 4 + 1], 0.f);
            a[q * 4 + 2] = fmaxf((accL[t * 33 + q * 4 + 2] + hv.z) * dv + sbc[q * 4 + 2], 0.f);
            a[q * 4 + 3] = fmaxf((accL[t * 33 + q * 4 + 3] + hv.w) * dv + sbc[q * 4 + 3], 0.f);
        }
        float t1[16];
#pragma unroll
        for (int j = 0; j < 16; j++) {
            float s = sb1[j];
            for (int k = 0; k < 32; k++) s += a[k] * sW1[k * 16 + j];
            t1[j] = fmaxf(s, 0.f);
        }
        float t2[8];
#pragma unroll
        for (int j = 0; j < 8; j++) {
            float s = sb2[j];
            for (int k = 0; k < 16; k++) s += t1[k] * sW2[k * 8 + j];
            t2[j] = fmaxf(s, 0.f);
        }
        float t3[10];
#pragma unroll
        for (int j = 0; j < 10; j++) {
            float s = sb3[j];
            for (int k = 0; k < 8; k++) s += t2[k] * sW3[k * 10 + j];
            t3[j] = s;
        }
        float m = t3[0];
#pragma unroll
        for (int j = 1; j < 10; j++) m = fmaxf(m, t3[j]);
        float se = 0.f;
#pragma unroll
        for (int j = 0; j < 10; j++) se += expf(t3[j] - m);
        float lse = logf(se) + m;
        float* op = out + (long)n * 10;
#pragma unroll
        for (int j = 0; j < 10; j++) op[j] = t3[j] - lse;
    }
}

extern "C" void kernel_launch(void* const* d_in, const int* in_sizes, int n_in,
                              void* d_out, int out_size, void* d_ws, size_t ws_size,
                              hipStream_t stream) {
    const float* x  = (const float*)d_in[0];
    const int*   ei = (const int*)d_in[1];  // [2, E] int32
    const float* Wc = (const float*)d_in[3];
    const float* bc = (const float*)d_in[4];
    const float* W1 = (const float*)d_in[5];
    const float* b1 = (const float*)d_in[6];
    const float* W2 = (const float*)d_in[7];
    const float* b2 = (const float*)d_in[8];
    const float* W3 = (const float*)d_in[9];
    const float* b3 = (const float*)d_in[10];
    float* out = (float*)d_out;

    // workspace layout (~20 MB); h2 first for 16B alignment
    float*    h2      = (float*)d_ws;                   // N*32
    unsigned* packed  = (unsigned*)(h2 + (long)N_NODES * F_H);  // E
    int*      counts  = (int*)(packed + N_EDGES);       // N
    float*    dinv    = (float*)(counts + N_NODES);     // N
    int*      bcnt    = (int*)(dinv + N_NODES);         // NBK
    int*      bbase   = bcnt + NBK;                     // NBK+1
    int*      gcursor = bbase + NBK + 1;                // NBK

    const int* srcp = ei;
    const int* dstp = ei + N_EDGES;

    hipMemsetAsync(counts, 0, N_NODES * sizeof(int), stream);
    hipMemsetAsync(bcnt, 0, NBK * sizeof(int), stream);
    bhist_kernel<<<256, 256, 0, stream>>>(dstp, bcnt);
    bscan_kernel<<<1, 1024, 0, stream>>>(bcnt, bbase, gcursor);
    binfill_kernel<<<BF_GRID, BF_B, 0, stream>>>(srcp, dstp, gcursor, counts, packed);
    dinv_kernel<<<(N_NODES + 255) / 256, 256, 0, stream>>>(counts, dinv);
    xw_kernel<<<(N_NODES + 7) / 8, 256, 0, stream>>>(x, Wc, dinv, h2);
    agg_kernel<<<NBK, AG_B, 0, stream>>>(bbase, packed, h2, dinv, bc, W1, b1, W2, b2,
                                         W3, b3, out);
}

// Round 4
// 242.942 us; speedup vs baseline: 2.4441x; 2.4441x over previous
//
#include <hip/hip_runtime.h>
#include <math.h>

#define N_NODES 100000
#define N_EDGES 1600000
#define F_IN 100
#define F_H 32

#define BKT_SHIFT 7
#define BKT_C 128                       // nodes per bucket
#define NBK 782                         // ceil(N_NODES / BKT_C)
#define BF_B 1024
#define BF_EPT 8
#define BF_TILE 8192                    // BF_B * BF_EPT
#define BF_GRID 196                     // ceil(N_EDGES / BF_TILE)
#define AG_B 512
#define AG_CAP 4096                     // LDS edge slots per chunk (avg bucket ~2048)
#define AG_EPT 8                        // AG_CAP / AG_B

// ---------------------------------------------- bucket histogram (LDS-binned)
__global__ void bhist_kernel(const int* __restrict__ dst, int* __restrict__ bcnt) {
    __shared__ int h[NBK];
    int t = threadIdx.x;
    for (int i = t; i < NBK; i += blockDim.x) h[i] = 0;
    __syncthreads();
    int stride = gridDim.x * blockDim.x;
    for (int e = blockIdx.x * blockDim.x + t; e < N_EDGES; e += stride)
        atomicAdd(&h[dst[e] >> BKT_SHIFT], 1);
    __syncthreads();
    for (int i = t; i < NBK; i += blockDim.x)
        if (h[i]) atomicAdd(&bcnt[i], h[i]);
}

// ---------------------------------------------- scan 782 bucket counts (1 block)
__global__ void bscan_kernel(const int* __restrict__ bcnt, int* __restrict__ bbase,
                             int* __restrict__ gcursor) {
    __shared__ int s[1024];
    int t = threadIdx.x;
    int v = (t < NBK) ? bcnt[t] : 0;
    s[t] = v;
    __syncthreads();
    for (int off = 1; off < 1024; off <<= 1) {
        int x = (t >= off) ? s[t - off] : 0;
        __syncthreads();
        s[t] += x;
        __syncthreads();
    }
    if (t < NBK) { int b = s[t] - v; bbase[t] = b; gcursor[t] = b; }
    if (t == 0) bbase[NBK] = N_EDGES;
}

// ---------------------------------------------- block-level counting sort into buckets
__global__ __launch_bounds__(BF_B) void binfill_kernel(
        const int* __restrict__ src, const int* __restrict__ dst,
        int* __restrict__ gcursor, unsigned* __restrict__ packed) {
    __shared__ int cnt[NBK];
    __shared__ int lbase[NBK];
    __shared__ int gbase[NBK];
    __shared__ int scanbuf[BF_B];
    __shared__ unsigned stage[BF_TILE];          // 32 KB
    __shared__ unsigned short stageB[BF_TILE];   // 16 KB
    __shared__ int tot;
    int t = threadIdx.x;
    long base = (long)blockIdx.x * BF_TILE;
    for (int i = t; i < NBK; i += BF_B) cnt[i] = 0;
    __syncthreads();
    int myb[BF_EPT]; int mypos[BF_EPT]; unsigned mypk[BF_EPT];
    for (int k = 0; k < BF_EPT; k++) {
        long e = base + t + (long)k * BF_B;      // coalesced
        myb[k] = -1;
        if (e < N_EDGES) {
            int d = dst[e];
            int sI = src[e];
            int b = d >> BKT_SHIFT;
            myb[k] = b;
            mypk[k] = (unsigned)sI | ((unsigned)(d & (BKT_C - 1)) << 17);
            mypos[k] = atomicAdd(&cnt[b], 1);
        }
    }
    __syncthreads();
    int v = (t < NBK) ? cnt[t] : 0;
    scanbuf[t] = v;
    __syncthreads();
    for (int off = 1; off < BF_B; off <<= 1) {
        int x = (t >= off) ? scanbuf[t - off] : 0;
        __syncthreads();
        scanbuf[t] += x;
        __syncthreads();
    }
    if (t < NBK) lbase[t] = scanbuf[t] - v;
    if (t == BF_B - 1) tot = scanbuf[t];
    __syncthreads();
    if (t < NBK && v > 0) gbase[t] = atomicAdd(&gcursor[t], v);
    for (int k = 0; k < BF_EPT; k++) {
        if (myb[k] >= 0) {
            int p = lbase[myb[k]] + mypos[k];
            stage[p] = mypk[k];
            stageB[p] = (unsigned short)myb[k];
        }
    }
    __syncthreads();
    int T = tot;
    for (int i = t; i < T; i += BF_B) {          // bucket runs -> contiguous writes
        int b = stageB[i];
        packed[gbase[b] + (i - lbase[b])] = stage[i];
    }
}

// ---------------------------------------------- per-node degree from binned edges
// one block per bucket: coalesced reads + LDS histogram (no random global atomics)
__global__ void deg_kernel(const int* __restrict__ bbase,
                           const unsigned* __restrict__ packed,
                           float* __restrict__ dinv) {
    __shared__ int cnt[BKT_C];
    int t = threadIdx.x;
    int b = blockIdx.x;
    if (t < BKT_C) cnt[t] = 0;
    __syncthreads();
    int beg = bbase[b], end = bbase[b + 1];
    for (int i = beg + t; i < end; i += blockDim.x)
        atomicAdd(&cnt[(packed[i] >> 17) & (BKT_C - 1)], 1);
    __syncthreads();
    int n = (b << BKT_SHIFT) + t;
    if (t < BKT_C && n < N_NODES) dinv[n] = rsqrtf((float)cnt[t] + 1.0f);
}

// ---------------------------------------------- h2 = (x @ Wc) * dinv[row]
__global__ void xw_kernel(const float* __restrict__ x, const float* __restrict__ W,
                          const float* __restrict__ dinv, float* __restrict__ h2) {
    __shared__ float Ws[F_IN * F_H];
    for (int i = threadIdx.x; i < F_IN * F_H; i += blockDim.x) Ws[i] = W[i];
    __syncthreads();
    int row = blockIdx.x * 8 + (threadIdx.x >> 5);
    int col = threadIdx.x & 31;
    if (row >= N_NODES) return;
    const float4* xr4 = (const float4*)(x + (long)row * F_IN);
    float s = 0.f;
#pragma unroll
    for (int k = 0; k < 25; k++) {
        float4 v = xr4[k];
        int k4 = k * 4;
        s += v.x * Ws[k4 * F_H + col];
        s += v.y * Ws[(k4 + 1) * F_H + col];
        s += v.z * Ws[(k4 + 2) * F_H + col];
        s += v.w * Ws[(k4 + 3) * F_H + col];
    }
    h2[row * F_H + col] = s * dinv[row];
}

// ---------------------------------------------- per-bucket: LDS counting sort ->
// per-(node,col) register accumulation -> fused MLP + log_softmax
__global__ __launch_bounds__(AG_B) void agg_kernel(
        const int* __restrict__ bbase, const unsigned* __restrict__ packed,
        const float* __restrict__ h2, const float* __restrict__ dinv,
        const float* __restrict__ bc,
        const float* __restrict__ W1, const float* __restrict__ b1,
        const float* __restrict__ W2, const float* __restrict__ b2,
        const float* __restrict__ W3, const float* __restrict__ b3,
        float* __restrict__ out) {
    __shared__ float accL[BKT_C * 33];           // 16.9 KB, stride-33 conflict-free
    __shared__ int esrc[AG_CAP];                 // 16 KB node-sorted src ids
    __shared__ int cnt[BKT_C];
    __shared__ int lbase[BKT_C];                 // inclusive scan of cnt
    __shared__ float sbc[32], sW1[512], sb1[16], sW2[128], sb2[8], sW3[80], sb3[10];
    int t = threadIdx.x;
    for (int i = t; i < BKT_C * 33; i += AG_B) accL[i] = 0.f;
    if (t < 32) sbc[t] = bc[t];
    if (t < 512) sW1[t] = W1[t];
    if (t < 16) sb1[t] = b1[t];
    if (t < 128) sW2[t] = W2[t];
    if (t < 8) sb2[t] = b2[t];
    if (t < 80) sW3[t] = W3[t];
    if (t < 10) sb3[t] = b3[t];

    int b = blockIdx.x;
    int beg = bbase[b], end = bbase[b + 1];
    int g = t >> 5, col = t & 31;                // 16 groups of 32 lanes

    for (int cbeg = beg; cbeg < end; cbeg += AG_CAP) {
        int cnum = min(end - cbeg, AG_CAP);
        if (t < BKT_C) cnt[t] = 0;
        __syncthreads();
        unsigned pk[AG_EPT]; int pos[AG_EPT];
#pragma unroll
        for (int k = 0; k < AG_EPT; k++) {
            int idx = t + k * AG_B;              // coalesced
            pk[k] = 0xFFFFFFFFu;
            if (idx < cnum) {
                unsigned p = packed[cbeg + idx];
                pk[k] = p;
                pos[k] = atomicAdd(&cnt[(p >> 17) & (BKT_C - 1)], 1);
            }
        }
        __syncthreads();
        // inclusive scan of cnt[0..127] into lbase (Hillis-Steele on 128 threads)
        if (t < BKT_C) lbase[t] = cnt[t];
        __syncthreads();
        for (int off = 1; off < BKT_C; off <<= 1) {
            int x = (t >= off && t < BKT_C) ? lbase[t - off] : 0;
            __syncthreads();
            if (t < BKT_C) lbase[t] += x;
            __syncthreads();
        }
        // scatter into node-sorted order
#pragma unroll
        for (int k = 0; k < AG_EPT; k++) {
            if (pk[k] != 0xFFFFFFFFu) {
                int lid = (pk[k] >> 17) & (BKT_C - 1);
                esrc[lbase[lid] - cnt[lid] + pos[k]] = (int)(pk[k] & 0x1FFFF);
            }
        }
        __syncthreads();
        // group g accumulates nodes g, g+16, ... (exclusive ownership of (node,col))
        for (int nd = g; nd < BKT_C; nd += 16) {
            int e = lbase[nd] - cnt[nd];
            int eend = lbase[nd];
            float s = 0.f;
            for (; e + 8 <= eend; e += 8) {      // 8 independent gathers in flight
                int a0 = esrc[e], a1 = esrc[e+1], a2 = esrc[e+2], a3 = esrc[e+3];
                int a4 = esrc[e+4], a5 = esrc[e+5], a6 = esrc[e+6], a7 = esrc[e+7];
                float v0 = h2[a0 * F_H + col], v1 = h2[a1 * F_H + col];
                float v2 = h2[a2 * F_H + col], v3 = h2[a3 * F_H + col];
                float v4 = h2[a4 * F_H + col], v5 = h2[a5 * F_H + col];
                float v6 = h2[a6 * F_H + col], v7 = h2[a7 * F_H + col];
                s += ((v0 + v1) + (v2 + v3)) + ((v4 + v5) + (v6 + v7));
            }
            for (; e + 4 <= eend; e += 4) {
                int a0 = esrc[e], a1 = esrc[e+1], a2 = esrc[e+2], a3 = esrc[e+3];
                float v0 = h2[a0 * F_H + col], v1 = h2[a1 * F_H + col];
                float v2 = h2[a2 * F_H + col], v3 = h2[a3 * F_H + col];
                s += (v0 + v1) + (v2 + v3);
            }
            for (; e < eend; e++) s += h2[esrc[e] * F_H + col];
            accL[nd * 33 + col] += s;
        }
        __syncthreads();
    }

    // epilogue: threads 0..127 each finish one node
    int n = (b << BKT_SHIFT) + t;
    if (t < BKT_C && n < N_NODES) {
        float dv = dinv[n];
        float a[32];
        const float4* hp = (const float4*)(h2 + (long)n * F_H);
#pragma unroll
        for (int q = 0; q < 8; q++) {
            float4 hv = hp[q];
            a[q*4+0] = fmaxf((accL[t*33 + q*4+0] + hv.x) * dv + sbc[q*4+0], 0.f);
            a[q*4+1] = fmaxf((accL[t*33 + q*4+1] + hv.y) * dv + sbc[q*4+1], 0.f);
            a[q*4+2] = fmaxf((accL[t*33 + q*4+2] + hv.z) * dv + sbc[q*4+2], 0.f);
            a[q*4+3] = fmaxf((accL[t*33 + q*4+3] + hv.w) * dv + sbc[q*4+3], 0.f);
        }
        float t1[16];
#pragma unroll
        for (int j = 0; j < 16; j++) {
            float s = sb1[j];
            for (int k = 0; k < 32; k++) s += a[k] * sW1[k * 16 + j];
            t1[j] = fmaxf(s, 0.f);
        }
        float t2[8];
#pragma unroll
        for (int j = 0; j < 8; j++) {
            float s = sb2[j];
            for (int k = 0; k < 16; k++) s += t1[k] * sW2[k * 8 + j];
            t2[j] = fmaxf(s, 0.f);
        }
        float t3[10];
#pragma unroll
        for (int j = 0; j < 10; j++) {
            float s = sb3[j];
            for (int k = 0; k < 8; k++) s += t2[k] * sW3[k * 10 + j];
            t3[j] = s;
        }
        float m = t3[0];
#pragma unroll
        for (int j = 1; j < 10; j++) m = fmaxf(m, t3[j]);
        float se = 0.f;
#pragma unroll
        for (int j = 0; j < 10; j++) se += expf(t3[j] - m);
        float lse = logf(se) + m;
        float* op = out + (long)n * 10;
#pragma unroll
        for (int j = 0; j < 10; j++) op[j] = t3[j] - lse;
    }
}

extern "C" void kernel_launch(void* const* d_in, const int* in_sizes, int n_in,
                              void* d_out, int out_size, void* d_ws, size_t ws_size,
                              hipStream_t stream) {
    const float* x  = (const float*)d_in[0];
    const int*   ei = (const int*)d_in[1];  // [2, E] int32
    const float* Wc = (const float*)d_in[3];
    const float* bc = (const float*)d_in[4];
    const float* W1 = (const float*)d_in[5];
    const float* b1 = (const float*)d_in[6];
    const float* W2 = (const float*)d_in[7];
    const float* b2 = (const float*)d_in[8];
    const float* W3 = (const float*)d_in[9];
    const float* b3 = (const float*)d_in[10];
    float* out = (float*)d_out;

    float*    h2      = (float*)d_ws;                           // N*32 (16B aligned)
    unsigned* packed  = (unsigned*)(h2 + (long)N_NODES * F_H);  // E
    float*    dinv    = (float*)(packed + N_EDGES);             // N
    int*      bcnt    = (int*)(dinv + N_NODES);                 // NBK
    int*      bbase   = bcnt + NBK;                             // NBK+1
    int*      gcursor = bbase + NBK + 1;                        // NBK

    const int* srcp = ei;
    const int* dstp = ei + N_EDGES;

    hipMemsetAsync(bcnt, 0, NBK * sizeof(int), stream);
    bhist_kernel<<<256, 256, 0, stream>>>(dstp, bcnt);
    bscan_kernel<<<1, 1024, 0, stream>>>(bcnt, bbase, gcursor);
    binfill_kernel<<<BF_GRID, BF_B, 0, stream>>>(srcp, dstp, gcursor, packed);
    deg_kernel<<<NBK, 256, 0, stream>>>(bbase, packed, dinv);
    xw_kernel<<<(N_NODES + 7) / 8, 256, 0, stream>>>(x, Wc, dinv, h2);
    agg_kernel<<<NBK, AG_B, 0, stream>>>(bbase, packed, h2, dinv, bc, W1, b1, W2, b2,
                                         W3, b3, out);
}

// Round 5
// 219.074 us; speedup vs baseline: 2.7104x; 1.1089x over previous
//
#include <hip/hip_runtime.h>
#include <math.h>

#define N_NODES 100000
#define N_EDGES 1600000
#define F_IN 100
#define F_H 32

#define BKT_SHIFT 7
#define BKT_C 128                       // nodes per bucket
#define NBK 782                         // ceil(N_NODES / BKT_C)
#define BF_B 1024
#define BF_EPT 8
#define BF_TILE 8192                    // BF_B * BF_EPT
#define BF_GRID 196                     // ceil(N_EDGES / BF_TILE)
#define AG_B 512
#define AG_CAP 4096                     // LDS edge slots per chunk (avg bucket ~2048)
#define AG_EPT 8                        // AG_CAP / AG_B

#define XW_B 256
#define XW_R 128                        // rows per block
#define XW_S 101                        // LDS row stride (odd -> conflict-free)

// ---------------------------------------------- bucket histogram (LDS-binned)
__global__ void bhist_kernel(const int* __restrict__ dst, int* __restrict__ bcnt) {
    __shared__ int h[NBK];
    int t = threadIdx.x;
    for (int i = t; i < NBK; i += blockDim.x) h[i] = 0;
    __syncthreads();
    int stride = gridDim.x * blockDim.x;
    for (int e = blockIdx.x * blockDim.x + t; e < N_EDGES; e += stride)
        atomicAdd(&h[dst[e] >> BKT_SHIFT], 1);
    __syncthreads();
    for (int i = t; i < NBK; i += blockDim.x)
        if (h[i]) atomicAdd(&bcnt[i], h[i]);
}

// ---------------------------------------------- scan 782 bucket counts (1 block)
__global__ void bscan_kernel(const int* __restrict__ bcnt, int* __restrict__ bbase,
                             int* __restrict__ gcursor) {
    __shared__ int s[1024];
    int t = threadIdx.x;
    int v = (t < NBK) ? bcnt[t] : 0;
    s[t] = v;
    __syncthreads();
    for (int off = 1; off < 1024; off <<= 1) {
        int x = (t >= off) ? s[t - off] : 0;
        __syncthreads();
        s[t] += x;
        __syncthreads();
    }
    if (t < NBK) { int b = s[t] - v; bbase[t] = b; gcursor[t] = b; }
    if (t == 0) bbase[NBK] = N_EDGES;
}

// ---------------------------------------------- block-level counting sort into buckets
__global__ __launch_bounds__(BF_B) void binfill_kernel(
        const int* __restrict__ src, const int* __restrict__ dst,
        int* __restrict__ gcursor, unsigned* __restrict__ packed) {
    __shared__ int cnt[NBK];
    __shared__ int lbase[NBK];
    __shared__ int gbase[NBK];
    __shared__ int scanbuf[BF_B];
    __shared__ unsigned stage[BF_TILE];          // 32 KB
    __shared__ unsigned short stageB[BF_TILE];   // 16 KB
    __shared__ int tot;
    int t = threadIdx.x;
    long base = (long)blockIdx.x * BF_TILE;
    for (int i = t; i < NBK; i += BF_B) cnt[i] = 0;
    __syncthreads();
    int myb[BF_EPT]; int mypos[BF_EPT]; unsigned mypk[BF_EPT];
    for (int k = 0; k < BF_EPT; k++) {
        long e = base + t + (long)k * BF_B;      // coalesced
        myb[k] = -1;
        if (e < N_EDGES) {
            int d = dst[e];
            int sI = src[e];
            int b = d >> BKT_SHIFT;
            myb[k] = b;
            mypk[k] = (unsigned)sI | ((unsigned)(d & (BKT_C - 1)) << 17);
            mypos[k] = atomicAdd(&cnt[b], 1);
        }
    }
    __syncthreads();
    int v = (t < NBK) ? cnt[t] : 0;
    scanbuf[t] = v;
    __syncthreads();
    for (int off = 1; off < BF_B; off <<= 1) {
        int x = (t >= off) ? scanbuf[t - off] : 0;
        __syncthreads();
        scanbuf[t] += x;
        __syncthreads();
    }
    if (t < NBK) lbase[t] = scanbuf[t] - v;
    if (t == BF_B - 1) tot = scanbuf[t];
    __syncthreads();
    if (t < NBK && v > 0) gbase[t] = atomicAdd(&gcursor[t], v);
    for (int k = 0; k < BF_EPT; k++) {
        if (myb[k] >= 0) {
            int p = lbase[myb[k]] + mypos[k];
            stage[p] = mypk[k];
            stageB[p] = (unsigned short)myb[k];
        }
    }
    __syncthreads();
    int T = tot;
    for (int i = t; i < T; i += BF_B) {          // bucket runs -> contiguous writes
        int b = stageB[i];
        packed[gbase[b] + (i - lbase[b])] = stage[i];
    }
}

// ---------------------------------------------- per-node degree from binned edges
__global__ void deg_kernel(const int* __restrict__ bbase,
                           const unsigned* __restrict__ packed,
                           float* __restrict__ dinv) {
    __shared__ int cnt[BKT_C];
    int t = threadIdx.x;
    int b = blockIdx.x;
    if (t < BKT_C) cnt[t] = 0;
    __syncthreads();
    int beg = bbase[b], end = bbase[b + 1];
    for (int i = beg + t; i < end; i += blockDim.x)
        atomicAdd(&cnt[(packed[i] >> 17) & (BKT_C - 1)], 1);
    __syncthreads();
    int n = (b << BKT_SHIFT) + t;
    if (t < BKT_C && n < N_NODES) dinv[n] = rsqrtf((float)cnt[t] + 1.0f);
}

// ---------------------------------------------- h2 = (x @ Wc) * dinv[row]
// 128 rows/block staged in LDS; thread owns (row, 16-col half); W via scalar loads
__global__ __launch_bounds__(XW_B) void xw_kernel(const float* __restrict__ x,
                                                  const float* __restrict__ W,
                                                  const float* __restrict__ dinv,
                                                  float* __restrict__ h2) {
    __shared__ float xs[XW_R * XW_S];            // 51.7 KB
    int t = threadIdx.x;
    int rbase = blockIdx.x * XW_R;
    int rows = min(XW_R, N_NODES - rbase);
    int total = rows * F_IN;                     // multiple of 4
    const float4* gx4 = (const float4*)(x + (long)rbase * F_IN);
    for (int i4 = t; i4 < (total >> 2); i4 += XW_B) {
        float4 v = gx4[i4];                      // coalesced: block's rows contiguous
        int i = i4 << 2;
        int r = i / F_IN;                        // float4 never crosses row (100%4==0)
        int k = i - r * F_IN;
        float* p = xs + r * XW_S + k;
        p[0] = v.x; p[1] = v.y; p[2] = v.z; p[3] = v.w;
    }
    __syncthreads();
    int r = t & (XW_R - 1);
    // wave-uniform column half -> W loads scalarize to s_load (no LDS/VMEM in loop)
    int colh16 = __builtin_amdgcn_readfirstlane((t >> 7) << 4);
    if (r < rows) {
        const float* Wp = W + colh16;
        float acc[16];
#pragma unroll
        for (int j = 0; j < 16; j++) acc[j] = 0.f;
        const float* xr = xs + r * XW_S;
#pragma unroll 4
        for (int k = 0; k < F_IN; k++) {
            float xv = xr[k];                    // 1 ds_read_b32 per 16 FMAs
#pragma unroll
            for (int j = 0; j < 16; j++)
                acc[j] = fmaf(xv, Wp[k * F_H + j], acc[j]);
        }
        int row = rbase + r;
        float dv = dinv[row];
        float* hp = h2 + (long)row * F_H + colh16;
#pragma unroll
        for (int j = 0; j < 16; j += 4) {
            float4 o;
            o.x = acc[j] * dv; o.y = acc[j + 1] * dv;
            o.z = acc[j + 2] * dv; o.w = acc[j + 3] * dv;
            ((float4*)hp)[j >> 2] = o;
        }
    }
}

// ---------------------------------------------- per-bucket: LDS counting sort ->
// per-(node,col) register accumulation -> fused MLP + log_softmax
__global__ __launch_bounds__(AG_B) void agg_kernel(
        const int* __restrict__ bbase, const unsigned* __restrict__ packed,
        const float* __restrict__ h2, const float* __restrict__ dinv,
        const float* __restrict__ bc,
        const float* __restrict__ W1, const float* __restrict__ b1,
        const float* __restrict__ W2, const float* __restrict__ b2,
        const float* __restrict__ W3, const float* __restrict__ b3,
        float* __restrict__ out) {
    __shared__ float accL[BKT_C * 33];           // 16.9 KB, stride-33 conflict-free
    __shared__ int esrc[AG_CAP];                 // 16 KB node-sorted src ids
    __shared__ int cnt[BKT_C];
    __shared__ int lbase[BKT_C];                 // inclusive scan of cnt
    __shared__ float sbc[32], sW1[512], sb1[16], sW2[128], sb2[8], sW3[80], sb3[10];
    int t = threadIdx.x;
    for (int i = t; i < BKT_C * 33; i += AG_B) accL[i] = 0.f;
    if (t < 32) sbc[t] = bc[t];
    if (t < 512) sW1[t] = W1[t];
    if (t < 16) sb1[t] = b1[t];
    if (t < 128) sW2[t] = W2[t];
    if (t < 8) sb2[t] = b2[t];
    if (t < 80) sW3[t] = W3[t];
    if (t < 10) sb3[t] = b3[t];

    int b = blockIdx.x;
    int beg = bbase[b], end = bbase[b + 1];
    int g = t >> 5, col = t & 31;                // 16 groups of 32 lanes

    for (int cbeg = beg; cbeg < end; cbeg += AG_CAP) {
        int cnum = min(end - cbeg, AG_CAP);
        if (t < BKT_C) cnt[t] = 0;
        __syncthreads();
        unsigned pk[AG_EPT]; int pos[AG_EPT];
#pragma unroll
        for (int k = 0; k < AG_EPT; k++) {
            int idx = t + k * AG_B;              // coalesced
            pk[k] = 0xFFFFFFFFu;
            if (idx < cnum) {
                unsigned p = packed[cbeg + idx];
                pk[k] = p;
                pos[k] = atomicAdd(&cnt[(p >> 17) & (BKT_C - 1)], 1);
            }
        }
        __syncthreads();
        if (t < BKT_C) lbase[t] = cnt[t];
        __syncthreads();
        for (int off = 1; off < BKT_C; off <<= 1) {
            int x = (t >= off && t < BKT_C) ? lbase[t - off] : 0;
            __syncthreads();
            if (t < BKT_C) lbase[t] += x;
            __syncthreads();
        }
#pragma unroll
        for (int k = 0; k < AG_EPT; k++) {
            if (pk[k] != 0xFFFFFFFFu) {
                int lid = (pk[k] >> 17) & (BKT_C - 1);
                esrc[lbase[lid] - cnt[lid] + pos[k]] = (int)(pk[k] & 0x1FFFF);
            }
        }
        __syncthreads();
        for (int nd = g; nd < BKT_C; nd += 16) {
            int e = lbase[nd] - cnt[nd];
            int eend = lbase[nd];
            float s = 0.f;
            for (; e + 8 <= eend; e += 8) {      // 8 independent gathers in flight
                int a0 = esrc[e], a1 = esrc[e+1], a2 = esrc[e+2], a3 = esrc[e+3];
                int a4 = esrc[e+4], a5 = esrc[e+5], a6 = esrc[e+6], a7 = esrc[e+7];
                float v0 = h2[a0 * F_H + col], v1 = h2[a1 * F_H + col];
                float v2 = h2[a2 * F_H + col], v3 = h2[a3 * F_H + col];
                float v4 = h2[a4 * F_H + col], v5 = h2[a5 * F_H + col];
                float v6 = h2[a6 * F_H + col], v7 = h2[a7 * F_H + col];
                s += ((v0 + v1) + (v2 + v3)) + ((v4 + v5) + (v6 + v7));
            }
            for (; e + 4 <= eend; e += 4) {
                int a0 = esrc[e], a1 = esrc[e+1], a2 = esrc[e+2], a3 = esrc[e+3];
                float v0 = h2[a0 * F_H + col], v1 = h2[a1 * F_H + col];
                float v2 = h2[a2 * F_H + col], v3 = h2[a3 * F_H + col];
                s += (v0 + v1) + (v2 + v3);
            }
            for (; e < eend; e++) s += h2[esrc[e] * F_H + col];
            accL[nd * 33 + col] += s;
        }
        __syncthreads();
    }

    int n = (b << BKT_SHIFT) + t;
    if (t < BKT_C && n < N_NODES) {
        float dv = dinv[n];
        float a[32];
        const float4* hp = (const float4*)(h2 + (long)n * F_H);
#pragma unroll
        for (int q = 0; q < 8; q++) {
            float4 hv = hp[q];
            a[q*4+0] = fmaxf((accL[t*33 + q*4+0] + hv.x) * dv + sbc[q*4+0], 0.f);
            a[q*4+1] = fmaxf((accL[t*33 + q*4+1] + hv.y) * dv + sbc[q*4+1], 0.f);
            a[q*4+2] = fmaxf((accL[t*33 + q*4+2] + hv.z) * dv + sbc[q*4+2], 0.f);
            a[q*4+3] = fmaxf((accL[t*33 + q*4+3] + hv.w) * dv + sbc[q*4+3], 0.f);
        }
        float t1[16];
#pragma unroll
        for (int j = 0; j < 16; j++) {
            float s = sb1[j];
            for (int k = 0; k < 32; k++) s += a[k] * sW1[k * 16 + j];
            t1[j] = fmaxf(s, 0.f);
        }
        float t2[8];
#pragma unroll
        for (int j = 0; j < 8; j++) {
            float s = sb2[j];
            for (int k = 0; k < 16; k++) s += t1[k] * sW2[k * 8 + j];
            t2[j] = fmaxf(s, 0.f);
        }
        float t3[10];
#pragma unroll
        for (int j = 0; j < 10; j++) {
            float s = sb3[j];
            for (int k = 0; k < 8; k++) s += t2[k] * sW3[k * 10 + j];
            t3[j] = s;
        }
        float m = t3[0];
#pragma unroll
        for (int j = 1; j < 10; j++) m = fmaxf(m, t3[j]);
        float se = 0.f;
#pragma unroll
        for (int j = 0; j < 10; j++) se += expf(t3[j] - m);
        float lse = logf(se) + m;
        float* op = out + (long)n * 10;
#pragma unroll
        for (int j = 0; j < 10; j++) op[j] = t3[j] - lse;
    }
}

extern "C" void kernel_launch(void* const* d_in, const int* in_sizes, int n_in,
                              void* d_out, int out_size, void* d_ws, size_t ws_size,
                              hipStream_t stream) {
    const float* x  = (const float*)d_in[0];
    const int*   ei = (const int*)d_in[1];  // [2, E] int32
    const float* Wc = (const float*)d_in[3];
    const float* bc = (const float*)d_in[4];
    const float* W1 = (const float*)d_in[5];
    const float* b1 = (const float*)d_in[6];
    const float* W2 = (const float*)d_in[7];
    const float* b2 = (const float*)d_in[8];
    const float* W3 = (const float*)d_in[9];
    const float* b3 = (const float*)d_in[10];
    float* out = (float*)d_out;

    float*    h2      = (float*)d_ws;                           // N*32 (16B aligned)
    unsigned* packed  = (unsigned*)(h2 + (long)N_NODES * F_H);  // E
    float*    dinv    = (float*)(packed + N_EDGES);             // N
    int*      bcnt    = (int*)(dinv + N_NODES);                 // NBK
    int*      bbase   = bcnt + NBK;                             // NBK+1
    int*      gcursor = bbase + NBK + 1;                        // NBK

    const int* srcp = ei;
    const int* dstp = ei + N_EDGES;

    hipMemsetAsync(bcnt, 0, NBK * sizeof(int), stream);
    bhist_kernel<<<256, 256, 0, stream>>>(dstp, bcnt);
    bscan_kernel<<<1, 1024, 0, stream>>>(bcnt, bbase, gcursor);
    binfill_kernel<<<BF_GRID, BF_B, 0, stream>>>(srcp, dstp, gcursor, packed);
    deg_kernel<<<NBK, 256, 0, stream>>>(bbase, packed, dinv);
    xw_kernel<<<(N_NODES + XW_R - 1) / XW_R, XW_B, 0, stream>>>(x, Wc, dinv, h2);
    agg_kernel<<<NBK, AG_B, 0, stream>>>(bbase, packed, h2, dinv, bc, W1, b1, W2, b2,
                                         W3, b3, out);
}